// Round 5
// baseline (889.393 us; speedup 1.0000x reference)
//
#include <hip/hip_runtime.h>

#define NN 8192
#define FF 256
#define OST 132   // osum LDS row stride (128 cols + 4 pad)

typedef _Float16 h8 __attribute__((ext_vector_type(8)));
typedef _Float16 h4 __attribute__((ext_vector_type(4)));
typedef float    f4 __attribute__((ext_vector_type(4)));
typedef int      i4v __attribute__((ext_vector_type(4)));

// monotone float<->uint encoding for atomicMax on fp32
__device__ __forceinline__ unsigned fenc(float x) {
  unsigned u = __float_as_uint(x);
  return (u & 0x80000000u) ? ~u : (u | 0x80000000u);
}
__device__ __forceinline__ float fdec(unsigned e) {
  unsigned u = (e & 0x80000000u) ? (e ^ 0x80000000u) : ~e;
  return __uint_as_float(u);
}

// ---------------- Kernel 1: Wh = h@W (fp32 vector), s1, s2(f16), wfrag -------
// grid 512 x 256 thr. Block = 16 rows of h = half of k-tile (blockIdx>>1).
// wfrag[(kt*16+n)*512 + lane*8 + j] = Wh[kt*32 + (lane>>4)*8 + j][n*16 + (lane&15)]
__global__ __launch_bounds__(256) void k_wh(
    const float* __restrict__ h, const float* __restrict__ W,
    const float* __restrict__ a, _Float16* __restrict__ wfrag,
    float* __restrict__ s1, _Float16* __restrict__ s2h,
    unsigned* __restrict__ s2maxe) {
  __shared__ float hs[16 * 256];        // 16 KB
  __shared__ _Float16 whs[16 * 264];    // 8.25 KB
  const int t = threadIdx.x;
  const int r0 = blockIdx.x * 16;
#pragma unroll
  for (int i = 0; i < 4; ++i) {
    int idx = i * 1024 + t * 4;
    *(f4*)&hs[idx] = *(const f4*)&h[(size_t)r0 * 256 + idx];
  }
  __syncthreads();
  const int lane = t & 63;
  const int wv = t >> 6;        // 0..3
  const int rg = wv * 4;        // 4 rows per wave
  const int c4 = lane * 4;      // 4 cols per lane
  float acc[4][4];
#pragma unroll
  for (int i = 0; i < 4; ++i)
#pragma unroll
    for (int k = 0; k < 4; ++k) acc[i][k] = 0.f;
  f4 w[8];
#pragma unroll
  for (int i = 0; i < 8; ++i) w[i] = *(const f4*)&W[i * 256 + c4];
  for (int f = 0; f < 256; f += 8) {
    f4 nw[8];
    if (f < 248) {
#pragma unroll
      for (int i = 0; i < 8; ++i) nw[i] = *(const f4*)&W[(f + 8 + i) * 256 + c4];
    }
#pragma unroll
    for (int i = 0; i < 4; ++i) {
      f4 h0 = *(const f4*)&hs[(rg + i) * 256 + f];
      f4 h1 = *(const f4*)&hs[(rg + i) * 256 + f + 4];
#pragma unroll
      for (int k = 0; k < 4; ++k)
        acc[i][k] += h0[0]*w[0][k] + h0[1]*w[1][k] + h0[2]*w[2][k] + h0[3]*w[3][k]
                   + h1[0]*w[4][k] + h1[1]*w[5][k] + h1[2]*w[6][k] + h1[3]*w[7][k];
    }
    if (f < 248) {
#pragma unroll
      for (int i = 0; i < 8; ++i) w[i] = nw[i];
    }
  }
  float a1v[4], a2v[4];
#pragma unroll
  for (int k = 0; k < 4; ++k) { a1v[k] = a[c4 + k]; a2v[k] = a[256 + c4 + k]; }
#pragma unroll
  for (int i = 0; i < 4; ++i) {
    h4 hh;
    float p1 = 0.f, p2 = 0.f;
#pragma unroll
    for (int k = 0; k < 4; ++k) {
      hh[k] = (_Float16)acc[i][k];
      p1 += acc[i][k] * a1v[k];
      p2 += acc[i][k] * a2v[k];
    }
    *(h4*)&whs[(rg + i) * 264 + c4] = hh;
#pragma unroll
    for (int off = 32; off; off >>= 1) {
      p1 += __shfl_xor(p1, off);
      p2 += __shfl_xor(p2, off);
    }
    if (lane == 0) {
      const int r = r0 + rg + i;
      s1[r] = p1;
      s2h[r] = (_Float16)p2;    // |s2| < ~10, exact to ~2^-11
      atomicMax(s2maxe, fenc(p2));
    }
  }
  __syncthreads();
  {
    const int kt = blockIdx.x >> 1;
    const int hb = blockIdx.x & 1;
    const int lp = hb * 32 + (t & 31);
    const int kb = ((t & 31) >> 4) * 8;
    const int m16e = t & 15;
#pragma unroll
    for (int p = 0; p < 2; ++p) {
      const int n = (t >> 5) + p * 8;
      h8 v;
#pragma unroll
      for (int j = 0; j < 8; ++j) v[j] = whs[(kb + j) * 264 + n * 16 + m16e];
      *(h8*)&wfrag[(((size_t)kt * 16 + n) << 9) + lp * 8] = v;
    }
  }
}

// ---------------- Kernel 2: fused masked-softmax attention (partial) ---------
// grid 2048 = (rt 0..511) x (c 0..1) x (kh 0..1); 256 thr; LB(256,6).
// Block: 16 rows x 128 cols x 4096 k (its kh-half). Wave wk owns 32 k-tiles.
// Per-iter issue order (vmcnt in-order retirement!): b-loads FIRST, then LDS
// s2 read (lgkm, decoupled), then adj d=2 prefetch LAST. Partial O/l go to
// global obuf/lbuf via atomicAdd (exactly 2 contributors each).
__global__ __launch_bounds__(256, 6) void k_gat(
    const int* __restrict__ adj, const _Float16* __restrict__ wfrag,
    const float* __restrict__ s1g, const _Float16* __restrict__ s2h,
    const unsigned* __restrict__ s2maxe,
    float* __restrict__ obuf, float* __restrict__ lbuf) {
  __shared__ _Float16 s2l[4096];     // 8 KB: this kh-half's s2
  __shared__ float osum[16 * OST];   // 8.4 KB
  __shared__ float lsh[16];
  const int t = threadIdx.x;
  const int lane = t & 63;
  const int wk = t >> 6;          // 0..3: k-quarter of the kh-half
  const int q = lane >> 4;        // 0..3
  const int m16 = lane & 15;
  const int b = blockIdx.x;
  const int sub = (b >> 3) & 3;
  const int c = sub & 1;                        // col-half
  const int kh = sub >> 1;                      // k-half
  const int rt = (b & 7) | ((b >> 5) << 3);     // row-tile 0..511
  const int r0 = rt * 16;

  // stage s2 (f16) for this kh-half into LDS
  {
    const h8* src = (const h8*)(s2h + kh * 4096);
    h8* dst = (h8*)s2l;
    dst[t] = src[t];
    dst[t + 256] = src[t + 256];
  }
  for (int i = t; i < 16 * OST; i += 256) osum[i] = 0.f;
  if (t < 16) lsh[t] = 0.f;
  __syncthreads();

  const float s2m = fdec(*s2maxe);
  const float s1a = s1g[r0 + m16];
  const float u0 = s1a + s2m;
  const float mi = fmaxf(u0, 0.2f * u0);   // >= leaky(s1a+s2[j]) for all j
  const float s1mi = s1a - mi;

  f4 acc[8];
#pragma unroll
  for (int n = 0; n < 8; ++n)
#pragma unroll
    for (int e = 0; e < 4; ++e) acc[n][e] = 0.f;
  float lsum = 0.f;

  const int* adjrow = adj + (size_t)(r0 + m16) * NN + kh * 4096 + q * 8;
  const int ktl0 = wk * 32;   // local k-tile base within kh-half

  // pipeline preload: adj depth-2, s2 depth-1 (LDS)
  i4v A1a = *(const i4v*)(adjrow + (ktl0 + 0) * 32);
  i4v A1b = *(const i4v*)(adjrow + (ktl0 + 0) * 32 + 4);
  i4v A2a = *(const i4v*)(adjrow + (ktl0 + 1) * 32);
  i4v A2b = *(const i4v*)(adjrow + (ktl0 + 1) * 32 + 4);
  h8 s2c = *(const h8*)&s2l[(ktl0 + 0) * 32 + q * 8];

#pragma unroll 4
  for (int it = 0; it < 32; ++it) {
    const int ktg = kh * 128 + ktl0 + it;
    const _Float16* wfc = wfrag + (((size_t)ktg * 16 + c * 8) << 9) + lane * 8;
    // (1) b-loads FIRST: oldest vm ops of this iter -> their wait drains
    //     nothing issued later (adj prefetch below stays in flight)
    h8 b0_[4], b1_[4];
#pragma unroll
    for (int n = 0; n < 4; ++n) b0_[n] = *(const h8*)(wfc + n * 512);
#pragma unroll
    for (int n = 0; n < 4; ++n) b1_[n] = *(const h8*)(wfc + (n + 4) * 512);
    // (2) LDS s2 prefetch for it+1 (lgkmcnt - independent of vmcnt chain)
    const int itn = (it < 31) ? it + 1 : it;
    h8 s2n = *(const h8*)&s2l[(ktl0 + itn) * 32 + q * 8];
    // (3) adj prefetch for it+2 (HBM; consumed at age 2 iters)
    const int itp = (it < 30) ? it + 2 : it;
    i4v Npa = *(const i4v*)(adjrow + (ktl0 + itp) * 32);
    i4v Npb = *(const i4v*)(adjrow + (ktl0 + itp) * 32 + 4);
    // (4) scores: p = exp(leaky(s1+s2) - mi); leaky(u) = u - 0.8*min(u,0)
    h8 af;
#pragma unroll
    for (int j = 0; j < 8; ++j) {
      const float s2v = (float)s2c[j];
      const float u = s1a + s2v;
      const float mn = fminf(u, 0.f);
      const float arg = s1mi + s2v - 0.8f * mn;
      float p = __expf(arg);
      const int msk = (j < 4) ? A1a[j] : A1b[j - 4];
      p = (msk > 0) ? p : 0.f;
      lsum += p;
      af[j] = (_Float16)p;
    }
    // (5) MFMA: b was issued at top of this iter, before adj(it+2)
#pragma unroll
    for (int n = 0; n < 4; ++n)
      acc[n] = __builtin_amdgcn_mfma_f32_16x16x32_f16(af, b0_[n], acc[n], 0, 0, 0);
#pragma unroll
    for (int n = 0; n < 4; ++n)
      acc[n + 4] = __builtin_amdgcn_mfma_f32_16x16x32_f16(af, b1_[n], acc[n + 4], 0, 0, 0);
    // (6) rotate pipeline regs
    A1a = A2a; A1b = A2b; A2a = Npa; A2b = Npb;
    s2c = s2n;
  }

  // partial softmax denominators for this kh-half
  lsum += __shfl_xor(lsum, 16);
  lsum += __shfl_xor(lsum, 32);
  if (q == 0) atomicAdd(&lsh[m16], lsum);
  // partial-O reduce across waves (C layout: col=lane&15, row=q*4+reg)
#pragma unroll
  for (int n = 0; n < 8; ++n)
#pragma unroll
    for (int v = 0; v < 4; ++v)
      atomicAdd(&osum[(q * 4 + v) * OST + n * 16 + m16], acc[n][v]);
  __syncthreads();

  // flush partials to global (exactly 2 contributors per element: kh=0,1)
  if (c == 0 && t < 16) atomicAdd(&lbuf[r0 + t], lsh[t]);
  {
    const int row = t >> 4;
    const int c0 = (t & 15) * 8;
#pragma unroll
    for (int i = 0; i < 8; ++i)
      atomicAdd(&obuf[(size_t)(r0 + row) * FF + c * 128 + c0 + i],
                osum[row * OST + c0 + i]);
  }
}

// ---------------- Kernel 3: normalize + elu ----------------------------------
__global__ __launch_bounds__(256) void k_fin(
    const float* __restrict__ obuf, const float* __restrict__ lbuf,
    float* __restrict__ out) {
  const int t = threadIdx.x;
  const int row = blockIdx.x * 16 + (t >> 4);
  const int c0 = (t & 15) * 16;
  const float linv = 1.0f / lbuf[row];
#pragma unroll
  for (int i = 0; i < 4; ++i) {
    f4 v = *(const f4*)&obuf[(size_t)row * FF + c0 + i * 4];
    f4 o;
#pragma unroll
    for (int e = 0; e < 4; ++e) {
      float x = v[e] * linv;
      o[e] = (x > 0.f) ? x : (__expf(x) - 1.f);
    }
    *(f4*)&out[(size_t)row * FF + c0 + i * 4] = o;
  }
}

extern "C" void kernel_launch(void* const* d_in, const int* in_sizes, int n_in,
                              void* d_out, int out_size, void* d_ws, size_t ws_size,
                              hipStream_t stream) {
  const float* h   = (const float*)d_in[0];
  const int*   adj = (const int*)d_in[1];
  const float* W   = (const float*)d_in[2];
  const float* a   = (const float*)d_in[3];
  float* out = (float*)d_out;

  char* ws = (char*)d_ws;
  _Float16* wfrag = (_Float16*)ws;                              // 4 MB
  float*    obuf  = (float*)(ws + (4u << 20));                  // 8 MB
  float*    lbuf  = (float*)(ws + (12u << 20));                 // 32 KB
  unsigned* s2me  = (unsigned*)(ws + (12u << 20) + 32768);      // 4 B (+pad 60)
  float*    s1    = (float*)(ws + (12u << 20) + 32832);         // 32 KB
  _Float16* s2h   = (_Float16*)(ws + (12u << 20) + 65600);      // 16 KB

  // zero obuf + lbuf + s2me in one async memset (fenc-domain -inf == 0)
  hipMemsetAsync(obuf, 0, (8u << 20) + 32768 + 64, stream);
  k_wh<<<512, 256, 0, stream>>>(h, W, a, wfrag, s1, s2h, s2me);
  k_gat<<<2048, 256, 0, stream>>>(adj, wfrag, s1, s2h, s2me, obuf, lbuf);
  k_fin<<<512, 256, 0, stream>>>(obuf, lbuf, out);
}

// Round 6
// 518.257 us; speedup vs baseline: 1.7161x; 1.7161x over previous
//
#include <hip/hip_runtime.h>

#define NN 8192
#define FF 256
#define PST 264   // P LDS row stride in halves (16B-aligned rows)

typedef _Float16 h8 __attribute__((ext_vector_type(8)));
typedef _Float16 h4 __attribute__((ext_vector_type(4)));
typedef float    f4 __attribute__((ext_vector_type(4)));
typedef int      i4v __attribute__((ext_vector_type(4)));

// monotone float<->uint encoding for atomicMax on fp32
__device__ __forceinline__ unsigned fenc(float x) {
  unsigned u = __float_as_uint(x);
  return (u & 0x80000000u) ? ~u : (u | 0x80000000u);
}
__device__ __forceinline__ float fdec(unsigned e) {
  unsigned u = (e & 0x80000000u) ? (e ^ 0x80000000u) : ~e;
  return __uint_as_float(u);
}

// ---------------- Kernel 1: Wh = h@W (fp32 vector), s1, s2(f16), wfrag -------
// grid 512 x 256 thr. Block = 16 rows of h = half of k-tile (blockIdx>>1).
// wfrag[(kt*16+n)*512 + lane*8 + j] = Wh[kt*32 + (lane>>4)*8 + j][n*16 + (lane&15)]
__global__ __launch_bounds__(256) void k_wh(
    const float* __restrict__ h, const float* __restrict__ W,
    const float* __restrict__ a, _Float16* __restrict__ wfrag,
    float* __restrict__ s1, _Float16* __restrict__ s2h,
    unsigned* __restrict__ s2maxe) {
  __shared__ float hs[16 * 256];        // 16 KB
  __shared__ _Float16 whs[16 * 264];    // 8.25 KB
  const int t = threadIdx.x;
  const int r0 = blockIdx.x * 16;
#pragma unroll
  for (int i = 0; i < 4; ++i) {
    int idx = i * 1024 + t * 4;
    *(f4*)&hs[idx] = *(const f4*)&h[(size_t)r0 * 256 + idx];
  }
  __syncthreads();
  const int lane = t & 63;
  const int wv = t >> 6;        // 0..3
  const int rg = wv * 4;
  const int c4 = lane * 4;
  float acc[4][4];
#pragma unroll
  for (int i = 0; i < 4; ++i)
#pragma unroll
    for (int k = 0; k < 4; ++k) acc[i][k] = 0.f;
  f4 w[8];
#pragma unroll
  for (int i = 0; i < 8; ++i) w[i] = *(const f4*)&W[i * 256 + c4];
  for (int f = 0; f < 256; f += 8) {
    f4 nw[8];
    if (f < 248) {
#pragma unroll
      for (int i = 0; i < 8; ++i) nw[i] = *(const f4*)&W[(f + 8 + i) * 256 + c4];
    }
#pragma unroll
    for (int i = 0; i < 4; ++i) {
      f4 h0 = *(const f4*)&hs[(rg + i) * 256 + f];
      f4 h1 = *(const f4*)&hs[(rg + i) * 256 + f + 4];
#pragma unroll
      for (int k = 0; k < 4; ++k)
        acc[i][k] += h0[0]*w[0][k] + h0[1]*w[1][k] + h0[2]*w[2][k] + h0[3]*w[3][k]
                   + h1[0]*w[4][k] + h1[1]*w[5][k] + h1[2]*w[6][k] + h1[3]*w[7][k];
    }
    if (f < 248) {
#pragma unroll
      for (int i = 0; i < 8; ++i) w[i] = nw[i];
    }
  }
  float a1v[4], a2v[4];
#pragma unroll
  for (int k = 0; k < 4; ++k) { a1v[k] = a[c4 + k]; a2v[k] = a[256 + c4 + k]; }
#pragma unroll
  for (int i = 0; i < 4; ++i) {
    h4 hh;
    float p1 = 0.f, p2 = 0.f;
#pragma unroll
    for (int k = 0; k < 4; ++k) {
      hh[k] = (_Float16)acc[i][k];
      p1 += acc[i][k] * a1v[k];
      p2 += acc[i][k] * a2v[k];
    }
    *(h4*)&whs[(rg + i) * 264 + c4] = hh;
#pragma unroll
    for (int off = 32; off; off >>= 1) {
      p1 += __shfl_xor(p1, off);
      p2 += __shfl_xor(p2, off);
    }
    if (lane == 0) {
      const int r = r0 + rg + i;
      s1[r] = p1;
      s2h[r] = (_Float16)p2;
      atomicMax(s2maxe, fenc(p2));
    }
  }
  __syncthreads();
  {
    const int kt = blockIdx.x >> 1;
    const int hb = blockIdx.x & 1;
    const int lp = hb * 32 + (t & 31);
    const int kb = ((t & 31) >> 4) * 8;
    const int m16e = t & 15;
#pragma unroll
    for (int p = 0; p < 2; ++p) {
      const int n = (t >> 5) + p * 8;
      h8 v;
#pragma unroll
      for (int j = 0; j < 8; ++j) v[j] = whs[(kb + j) * 264 + n * 16 + m16e];
      *(h8*)&wfrag[(((size_t)kt * 16 + n) << 9) + lp * 8] = v;
    }
  }
}

// ---------------- Kernel 2: fused attention, n-split waves + P via LDS -------
// grid 512 = (rt 0..255) x (kh 0..1); 512 thr (8 waves); 2 blocks/CU.
// Block: 32 rows x 256 cols x 4096 k. Per 256-k period: each wave computes
// P for rows 4w..4w+3 (once, no redundancy) into LDS dbuf; ONE barrier; all
// waves MFMA their 32-col slice (B from L2-resident wfrag). adj is read
// exactly once chip-wide. Partials (kh=0 -> out, kh=1 -> o1) by plain stores.
__global__ __launch_bounds__(512, 4) void k_gat(
    const int* __restrict__ adj, const _Float16* __restrict__ wfrag,
    const float* __restrict__ s1g, const _Float16* __restrict__ s2h,
    const unsigned* __restrict__ s2maxe,
    float* __restrict__ o0, float* __restrict__ o1,
    float* __restrict__ lbuf) {
  __shared__ _Float16 P[2][32 * PST];   // 33 KB
  __shared__ _Float16 s2l[4096];        // 8 KB
  const int t = threadIdx.x;
  const int lane = t & 63;
  const int w = t >> 6;          // 0..7: score rows 4w..4w+3; cols [32w,32w+32)
  const int q = lane >> 4;       // 0..3
  const int m16 = lane & 15;
  const int rt = (int)blockIdx.x >> 1;
  const int kh = (int)blockIdx.x & 1;
  const int r0 = rt * 32;

  ((h8*)s2l)[t] = ((const h8*)(s2h + kh * 4096))[t];   // stage kh-half s2

  const int srow = 4 * w + q;                // this lane's score row (local)
  const float s2m = fdec(*s2maxe);
  const float s1r = s1g[r0 + srow];
  const float u0 = s1r + s2m;
  const float mi = fmaxf(u0, 0.2f * u0);     // >= leaky(s1r+s2[j]) for all j
  const float s1mi = s1r - mi;

  f4 acc[2][2];
#pragma unroll
  for (int m = 0; m < 2; ++m)
#pragma unroll
    for (int n = 0; n < 2; ++n)
#pragma unroll
      for (int e = 0; e < 4; ++e) acc[m][n][e] = 0.f;
  float lsum = 0.f;

  const int* adjp = adj + (size_t)(r0 + srow) * NN + kh * 4096 + m16 * 16;
  __syncthreads();   // s2l ready

  for (int p = 0; p < 16; ++p) {
    _Float16* Pb = &P[p & 1][0];
    // ---- score phase: rows 4w..4w+3, k in [p*256, p*256+256) (local)
    const i4v a0 = *(const i4v*)(adjp + p * 256);
    const i4v a1 = *(const i4v*)(adjp + p * 256 + 4);
    const i4v a2 = *(const i4v*)(adjp + p * 256 + 8);
    const i4v a3 = *(const i4v*)(adjp + p * 256 + 12);
    const h8 s2a = *(const h8*)&s2l[p * 256 + m16 * 16];
    const h8 s2b = *(const h8*)&s2l[p * 256 + m16 * 16 + 8];
    h8 pa, pb;
    // p = exp(leaky(s1+s2) - mi); leaky(u) = u - 0.8*min(u,0); one exp
#pragma unroll
    for (int j = 0; j < 4; ++j) {
      const float s2v = (float)s2a[j];
      const float arg = s1mi + s2v - 0.8f * fminf(s1r + s2v, 0.f);
      const float pv = (a0[j] > 0) ? __expf(arg) : 0.f;
      lsum += pv; pa[j] = (_Float16)pv;
    }
#pragma unroll
    for (int j = 0; j < 4; ++j) {
      const float s2v = (float)s2a[4 + j];
      const float arg = s1mi + s2v - 0.8f * fminf(s1r + s2v, 0.f);
      const float pv = (a1[j] > 0) ? __expf(arg) : 0.f;
      lsum += pv; pa[4 + j] = (_Float16)pv;
    }
#pragma unroll
    for (int j = 0; j < 4; ++j) {
      const float s2v = (float)s2b[j];
      const float arg = s1mi + s2v - 0.8f * fminf(s1r + s2v, 0.f);
      const float pv = (a2[j] > 0) ? __expf(arg) : 0.f;
      lsum += pv; pb[j] = (_Float16)pv;
    }
#pragma unroll
    for (int j = 0; j < 4; ++j) {
      const float s2v = (float)s2b[4 + j];
      const float arg = s1mi + s2v - 0.8f * fminf(s1r + s2v, 0.f);
      const float pv = (a3[j] > 0) ? __expf(arg) : 0.f;
      lsum += pv; pb[4 + j] = (_Float16)pv;
    }
    *(h8*)&Pb[srow * PST + m16 * 16] = pa;
    *(h8*)&Pb[srow * PST + m16 * 16 + 8] = pb;
    __syncthreads();   // P ready; also guards buffer reuse (dbuf gives slack)
    // ---- MFMA phase: this wave's 2 n-tiles (cols 32w..32w+32), 8 k-subtiles
    const _Float16* wfb = wfrag
        + ((((size_t)(kh * 128 + p * 8)) * 16 + 2 * w) << 9) + lane * 8;
    h8 b0 = *(const h8*)(wfb);
    h8 b1 = *(const h8*)(wfb + 512);
#pragma unroll
    for (int ks = 0; ks < 8; ++ks) {
      h8 nb0 = b0, nb1 = b1;
      if (ks < 7) {
        nb0 = *(const h8*)(wfb + (ks + 1) * 8192);
        nb1 = *(const h8*)(wfb + (ks + 1) * 8192 + 512);
      }
      const h8 A0 = *(const h8*)&Pb[m16 * PST + ks * 32 + q * 8];
      const h8 A1 = *(const h8*)&Pb[(16 + m16) * PST + ks * 32 + q * 8];
      acc[0][0] = __builtin_amdgcn_mfma_f32_16x16x32_f16(A0, b0, acc[0][0], 0, 0, 0);
      acc[0][1] = __builtin_amdgcn_mfma_f32_16x16x32_f16(A0, b1, acc[0][1], 0, 0, 0);
      acc[1][0] = __builtin_amdgcn_mfma_f32_16x16x32_f16(A1, b0, acc[1][0], 0, 0, 0);
      acc[1][1] = __builtin_amdgcn_mfma_f32_16x16x32_f16(A1, b1, acc[1][1], 0, 0, 0);
      b0 = nb0; b1 = nb1;
    }
  }

  // partial softmax denominator for this kh-half (row srow): reduce over m16
  lsum += __shfl_xor(lsum, 1);
  lsum += __shfl_xor(lsum, 2);
  lsum += __shfl_xor(lsum, 4);
  lsum += __shfl_xor(lsum, 8);
  if (m16 == 0) lbuf[kh * NN + r0 + srow] = lsum;

  // partial O: plain stores, each element written by exactly one thread/kh
  float* ob = kh ? o1 : o0;
#pragma unroll
  for (int m = 0; m < 2; ++m)
#pragma unroll
    for (int n = 0; n < 2; ++n)
#pragma unroll
      for (int v = 0; v < 4; ++v)
        ob[(size_t)(r0 + m * 16 + q * 4 + v) * FF + w * 32 + n * 16 + m16] =
            acc[m][n][v];
}

// ---------------- Kernel 3: combine halves, normalize, elu -------------------
__global__ __launch_bounds__(256) void k_fin(
    float* __restrict__ out, const float* __restrict__ o1,
    const float* __restrict__ lbuf) {
  const int t = threadIdx.x;
  const int row = blockIdx.x * 16 + (t >> 4);
  const int c0 = (t & 15) * 16;
  const float linv = 1.0f / (lbuf[row] + lbuf[NN + row]);
#pragma unroll
  for (int i = 0; i < 4; ++i) {
    f4 v0 = *(const f4*)&out[(size_t)row * FF + c0 + i * 4];
    f4 v1 = *(const f4*)&o1[(size_t)row * FF + c0 + i * 4];
    f4 o;
#pragma unroll
    for (int e = 0; e < 4; ++e) {
      float x = (v0[e] + v1[e]) * linv;
      o[e] = (x > 0.f) ? x : (__expf(x) - 1.f);
    }
    *(f4*)&out[(size_t)row * FF + c0 + i * 4] = o;
  }
}

extern "C" void kernel_launch(void* const* d_in, const int* in_sizes, int n_in,
                              void* d_out, int out_size, void* d_ws, size_t ws_size,
                              hipStream_t stream) {
  const float* h   = (const float*)d_in[0];
  const int*   adj = (const int*)d_in[1];
  const float* W   = (const float*)d_in[2];
  const float* a   = (const float*)d_in[3];
  float* out = (float*)d_out;

  char* ws = (char*)d_ws;
  _Float16* wfrag = (_Float16*)ws;                                // 4 MB
  float*    o1    = (float*)(ws + (4u << 20));                    // 8 MB (kh=1 partial)
  float*    lbuf  = (float*)(ws + (12u << 20));                   // 64 KB (2 x 8192 f32)
  unsigned* s2me  = (unsigned*)(ws + (12u << 20) + 65536);        // 4 B (+60 pad)
  float*    s1    = (float*)(ws + (12u << 20) + 65600);           // 32 KB
  _Float16* s2h   = (_Float16*)(ws + (12u << 20) + 65600 + 32768);// 16 KB

  hipMemsetAsync(s2me, 0, 4, stream);   // fenc-domain -inf
  k_wh<<<512, 256, 0, stream>>>(h, W, a, wfrag, s1, s2h, s2me);
  k_gat<<<512, 512, 0, stream>>>(adj, wfrag, s1, s2h, s2me, out, o1, lbuf);
  k_fin<<<512, 256, 0, stream>>>(out, o1, lbuf);
}

// Round 7
// 502.662 us; speedup vs baseline: 1.7694x; 1.0310x over previous
//
#include <hip/hip_runtime.h>

#define NN 8192
#define FF 256
#define PST 136   // P LDS row stride in halves (128 + 8 pad, 16B-aligned)

typedef _Float16 h8 __attribute__((ext_vector_type(8)));
typedef _Float16 h4 __attribute__((ext_vector_type(4)));
typedef float    f4 __attribute__((ext_vector_type(4)));
typedef int      i4v __attribute__((ext_vector_type(4)));

// monotone float<->uint encoding for atomicMax on fp32
__device__ __forceinline__ unsigned fenc(float x) {
  unsigned u = __float_as_uint(x);
  return (u & 0x80000000u) ? ~u : (u | 0x80000000u);
}
__device__ __forceinline__ float fdec(unsigned e) {
  unsigned u = (e & 0x80000000u) ? (e ^ 0x80000000u) : ~e;
  return __uint_as_float(u);
}

// lgkm-only barrier (CK block_sync_lds pattern): publishes LDS writes without
// draining vmem (plain __syncthreads emits s_waitcnt vmcnt(0) -> kills the
// adj prefetch pipeline).
__device__ __forceinline__ void sync_lds() {
  __builtin_amdgcn_s_waitcnt(0xc07f);   // lgkmcnt(0), vmcnt/expcnt ignored
  __builtin_amdgcn_s_barrier();
}

// ---------------- Kernel 1: Wh = h@W (fp32 vector), s1, s2(f16), wfrag -------
// grid 512 x 256 thr. Block = 16 rows of h = half of k-tile (blockIdx>>1).
// wfrag[(kt*16+n)*512 + lane*8 + j] = Wh[kt*32 + (lane>>4)*8 + j][n*16 + (lane&15)]
__global__ __launch_bounds__(256) void k_wh(
    const float* __restrict__ h, const float* __restrict__ W,
    const float* __restrict__ a, _Float16* __restrict__ wfrag,
    float* __restrict__ s1, _Float16* __restrict__ s2h,
    unsigned* __restrict__ s2maxe) {
  __shared__ float hs[16 * 256];        // 16 KB
  __shared__ _Float16 whs[16 * 264];    // 8.25 KB
  const int t = threadIdx.x;
  const int r0 = blockIdx.x * 16;
#pragma unroll
  for (int i = 0; i < 4; ++i) {
    int idx = i * 1024 + t * 4;
    *(f4*)&hs[idx] = *(const f4*)&h[(size_t)r0 * 256 + idx];
  }
  __syncthreads();
  const int lane = t & 63;
  const int wv = t >> 6;        // 0..3
  const int rg = wv * 4;
  const int c4 = lane * 4;
  float acc[4][4];
#pragma unroll
  for (int i = 0; i < 4; ++i)
#pragma unroll
    for (int k = 0; k < 4; ++k) acc[i][k] = 0.f;
  f4 w[8];
#pragma unroll
  for (int i = 0; i < 8; ++i) w[i] = *(const f4*)&W[i * 256 + c4];
  for (int f = 0; f < 256; f += 8) {
    f4 nw[8];
    if (f < 248) {
#pragma unroll
      for (int i = 0; i < 8; ++i) nw[i] = *(const f4*)&W[(f + 8 + i) * 256 + c4];
    }
#pragma unroll
    for (int i = 0; i < 4; ++i) {
      f4 h0 = *(const f4*)&hs[(rg + i) * 256 + f];
      f4 h1 = *(const f4*)&hs[(rg + i) * 256 + f + 4];
#pragma unroll
      for (int k = 0; k < 4; ++k)
        acc[i][k] += h0[0]*w[0][k] + h0[1]*w[1][k] + h0[2]*w[2][k] + h0[3]*w[3][k]
                   + h1[0]*w[4][k] + h1[1]*w[5][k] + h1[2]*w[6][k] + h1[3]*w[7][k];
    }
    if (f < 248) {
#pragma unroll
      for (int i = 0; i < 8; ++i) w[i] = nw[i];
    }
  }
  float a1v[4], a2v[4];
#pragma unroll
  for (int k = 0; k < 4; ++k) { a1v[k] = a[c4 + k]; a2v[k] = a[256 + c4 + k]; }
#pragma unroll
  for (int i = 0; i < 4; ++i) {
    h4 hh;
    float p1 = 0.f, p2 = 0.f;
#pragma unroll
    for (int k = 0; k < 4; ++k) {
      hh[k] = (_Float16)acc[i][k];
      p1 += acc[i][k] * a1v[k];
      p2 += acc[i][k] * a2v[k];
    }
    *(h4*)&whs[(rg + i) * 264 + c4] = hh;
#pragma unroll
    for (int off = 32; off; off >>= 1) {
      p1 += __shfl_xor(p1, off);
      p2 += __shfl_xor(p2, off);
    }
    if (lane == 0) {
      const int r = r0 + rg + i;
      s1[r] = p1;
      s2h[r] = (_Float16)p2;
      atomicMax(s2maxe, fenc(p2));
    }
  }
  __syncthreads();
  {
    const int kt = blockIdx.x >> 1;
    const int hb = blockIdx.x & 1;
    const int lp = hb * 32 + (t & 31);
    const int kb = ((t & 31) >> 4) * 8;
    const int m16e = t & 15;
#pragma unroll
    for (int p = 0; p < 2; ++p) {
      const int n = (t >> 5) + p * 8;
      h8 v;
#pragma unroll
      for (int j = 0; j < 8; ++j) v[j] = whs[(kb + j) * 264 + n * 16 + m16e];
      *(h8*)&wfrag[(((size_t)kt * 16 + n) << 9) + lp * 8] = v;
    }
  }
}

// ---------------- Kernel 2: fused attention ----------------------------------
// grid 512 = (rt 0..255) x (kh 0..1); 512 thr; LB(512,4) -> 2 blocks/CU.
// Block: 32 rows x 256 cols x 4096 k. Period = 128 k (32 periods). Per period:
//  (1) 8 B-frag loads (L2) issued FIRST (oldest vmem of the period)
//  (2) adj loads for period p+1 (HBM, consumed a full period later)
//  (3) scores from adj regs loaded last period + s2 from LDS -> P (LDS dbuf)
//  (4) lgkm-only barrier (adj/B stay in flight!)
//  (5) 8 MFMA; B-waits leave the adj prefetch outstanding (vmcnt(2))
__global__ __launch_bounds__(512, 4) void k_gat(
    const int* __restrict__ adj, const _Float16* __restrict__ wfrag,
    const float* __restrict__ s1g, const _Float16* __restrict__ s2h,
    const unsigned* __restrict__ s2maxe,
    float* __restrict__ o0, float* __restrict__ o1,
    float* __restrict__ lbuf) {
  __shared__ _Float16 P[2][32 * PST];   // 17 KB
  __shared__ _Float16 s2l[4096];        // 8 KB
  const int t = threadIdx.x;
  const int lane = t & 63;
  const int w = t >> 6;          // 0..7: score rows 4w..4w+3; cols [32w,32w+32)
  const int q = lane >> 4;       // 0..3
  const int m16 = lane & 15;
  const int rt = (int)blockIdx.x >> 1;
  const int kh = (int)blockIdx.x & 1;
  const int r0 = rt * 32;

  ((h8*)s2l)[t] = ((const h8*)(s2h + kh * 4096))[t];   // stage kh-half s2

  const int srow = 4 * w + q;                // this lane's score row (local)
  const float s2m = fdec(*s2maxe);
  const float s1r = s1g[r0 + srow];
  const float u0 = s1r + s2m;
  const float mi = fmaxf(u0, 0.2f * u0);     // >= leaky(s1r+s2[j]) for all j
  const float s1mi = s1r - mi;

  f4 acc[2][2];
#pragma unroll
  for (int m = 0; m < 2; ++m)
#pragma unroll
    for (int n = 0; n < 2; ++n)
#pragma unroll
      for (int e = 0; e < 4; ++e) acc[m][n][e] = 0.f;
  float lsum = 0.f;

  const int* adjp = adj + (size_t)(r0 + srow) * NN + kh * 4096 + m16 * 8;
  __syncthreads();   // s2l ready (once; full drain harmless here)

  // preload adj for period 0
  i4v c0 = *(const i4v*)(adjp);
  i4v c1 = *(const i4v*)(adjp + 4);

  for (int p = 0; p < 32; ++p) {
    // (1) B-frags for this period: 4 k-subtiles x 2 n-tiles, coalesced L2 loads
    const _Float16* wfb =
        wfrag + ((((size_t)(kh * 128 + p * 4)) * 16 + 2 * w) << 9) + lane * 8;
    h8 bb[8];
#pragma unroll
    for (int ks = 0; ks < 4; ++ks) {
      bb[2 * ks]     = *(const h8*)(wfb + ks * 8192);
      bb[2 * ks + 1] = *(const h8*)(wfb + ks * 8192 + 512);
    }
    // (2) adj prefetch for p+1 (HBM; consumed next period)
    i4v n0 = c0, n1 = c1;
    if (p < 31) {
      n0 = *(const i4v*)(adjp + (p + 1) * 128);
      n1 = *(const i4v*)(adjp + (p + 1) * 128 + 4);
    }
    // (3) scores: p = exp(leaky(s1+s2) - mi); leaky(u) = u - 0.8*min(u,0)
    const h8 s2c = *(const h8*)&s2l[p * 128 + m16 * 8];
    h8 pa;
#pragma unroll
    for (int j = 0; j < 8; ++j) {
      const float s2v = (float)s2c[j];
      const float u = s1r + s2v;
      const float arg = s1mi + s2v - 0.8f * fminf(u, 0.f);
      const int msk = (j < 4) ? c0[j] : c1[j - 4];
      const float pv = (msk > 0) ? __expf(arg) : 0.f;
      lsum += pv;
      pa[j] = (_Float16)pv;
    }
    _Float16* Pb = &P[p & 1][0];
    *(h8*)&Pb[srow * PST + m16 * 8] = pa;
    // (4) publish P without draining vmem
    sync_lds();
    // (5) MFMA: A from LDS, B from regs (issued at (1), ~score-phase old)
#pragma unroll
    for (int ks = 0; ks < 4; ++ks) {
      const h8 A0 = *(const h8*)&Pb[m16 * PST + ks * 32 + q * 8];
      const h8 A1 = *(const h8*)&Pb[(16 + m16) * PST + ks * 32 + q * 8];
      acc[0][0] = __builtin_amdgcn_mfma_f32_16x16x32_f16(A0, bb[2*ks],   acc[0][0], 0, 0, 0);
      acc[0][1] = __builtin_amdgcn_mfma_f32_16x16x32_f16(A0, bb[2*ks+1], acc[0][1], 0, 0, 0);
      acc[1][0] = __builtin_amdgcn_mfma_f32_16x16x32_f16(A1, bb[2*ks],   acc[1][0], 0, 0, 0);
      acc[1][1] = __builtin_amdgcn_mfma_f32_16x16x32_f16(A1, bb[2*ks+1], acc[1][1], 0, 0, 0);
    }
    c0 = n0; c1 = n1;
  }

  // partial softmax denominator (row srow): reduce over the 16 m16 lanes
  lsum += __shfl_xor(lsum, 1);
  lsum += __shfl_xor(lsum, 2);
  lsum += __shfl_xor(lsum, 4);
  lsum += __shfl_xor(lsum, 8);
  if (m16 == 0) lbuf[kh * NN + r0 + srow] = lsum;

  // partial O: plain stores (each element written once per kh)
  float* ob = kh ? o1 : o0;
#pragma unroll
  for (int m = 0; m < 2; ++m)
#pragma unroll
    for (int n = 0; n < 2; ++n)
#pragma unroll
      for (int v = 0; v < 4; ++v)
        ob[(size_t)(r0 + m * 16 + q * 4 + v) * FF + w * 32 + n * 16 + m16] =
            acc[m][n][v];
}

// ---------------- Kernel 3: combine halves, normalize, elu -------------------
__global__ __launch_bounds__(256) void k_fin(
    float* __restrict__ out, const float* __restrict__ o1,
    const float* __restrict__ lbuf) {
  const int t = threadIdx.x;
  const int row = blockIdx.x * 16 + (t >> 4);
  const int c0 = (t & 15) * 16;
  const float linv = 1.0f / (lbuf[row] + lbuf[NN + row]);
#pragma unroll
  for (int i = 0; i < 4; ++i) {
    f4 v0 = *(const f4*)&out[(size_t)row * FF + c0 + i * 4];
    f4 v1 = *(const f4*)&o1[(size_t)row * FF + c0 + i * 4];
    f4 o;
#pragma unroll
    for (int e = 0; e < 4; ++e) {
      float x = (v0[e] + v1[e]) * linv;
      o[e] = (x > 0.f) ? x : (__expf(x) - 1.f);
    }
    *(f4*)&out[(size_t)row * FF + c0 + i * 4] = o;
  }
}

extern "C" void kernel_launch(void* const* d_in, const int* in_sizes, int n_in,
                              void* d_out, int out_size, void* d_ws, size_t ws_size,
                              hipStream_t stream) {
  const float* h   = (const float*)d_in[0];
  const int*   adj = (const int*)d_in[1];
  const float* W   = (const float*)d_in[2];
  const float* a   = (const float*)d_in[3];
  float* out = (float*)d_out;

  char* ws = (char*)d_ws;
  _Float16* wfrag = (_Float16*)ws;                                // 4 MB
  float*    o1    = (float*)(ws + (4u << 20));                    // 8 MB (kh=1 partial)
  float*    lbuf  = (float*)(ws + (12u << 20));                   // 64 KB (2 x 8192 f32)
  unsigned* s2me  = (unsigned*)(ws + (12u << 20) + 65536);        // 4 B (+60 pad)
  float*    s1    = (float*)(ws + (12u << 20) + 65600);           // 32 KB
  _Float16* s2h   = (_Float16*)(ws + (12u << 20) + 65600 + 32768);// 16 KB

  hipMemsetAsync(s2me, 0, 4, stream);   // fenc-domain -inf
  k_wh<<<512, 256, 0, stream>>>(h, W, a, wfrag, s1, s2h, s2me);
  k_gat<<<512, 512, 0, stream>>>(adj, wfrag, s1, s2h, s2me, out, o1, lbuf);
  k_fin<<<512, 256, 0, stream>>>(out, o1, lbuf);
}